// Round 1
// baseline (576.020 us; speedup 1.0000x reference)
//
#include <hip/hip_runtime.h>

typedef __attribute__((ext_vector_type(4))) float f32x4;
typedef __attribute__((ext_vector_type(8))) __bf16 bf16x8;

__device__ __forceinline__ ushort f2bf(float f) {
  unsigned int u = __float_as_uint(f);
  return (ushort)((u + 0x7FFFu + ((u >> 16) & 1u)) >> 16);
}

// async global->LDS, 16B per lane; LDS dst must be wave-uniform base (HW adds lane*16)
__device__ __forceinline__ void async_cp16(const void* g, void* l) {
  __builtin_amdgcn_global_load_lds(
      (const __attribute__((address_space(1))) void*)g,
      (__attribute__((address_space(3))) void*)l, 16, 0, 0);
}

__global__ __launch_bounds__(256) void cast_bf16_kernel(const float* __restrict__ in,
                                                        ushort* __restrict__ out, int n4) {
  int i = blockIdx.x * 256 + threadIdx.x;
  if (i < n4) {
    float4 v = ((const float4*)in)[i];
    ushort4 o;
    o.x = f2bf(v.x); o.y = f2bf(v.y); o.z = f2bf(v.z); o.w = f2bf(v.w);
    ((ushort4*)out)[i] = o;
  }
}

// C[m,n] = sum_k A[m,k] * W[n,k].  A:[M,K] bf16 row-major, W:[N,K] bf16 row-major.
// MODE 0: bf16 out row-major [M,N]
// MODE 1: fp32 out row-major [M,N]
// MODE 2: bf16 out per-head transposed: row=(b,s), col=(h,d) -> out[((b*16+h)*64+d)*2048 + s]
template <int MODE>
__global__ __launch_bounds__(256) void gemm_bt(const ushort* __restrict__ A,
                                               const ushort* __restrict__ W,
                                               void* __restrict__ Cout,
                                               int M, int N, int K) {
  // chunk-blocked LDS tile: elem(row,k) at ((k>>3)*128 + row)*8 + (k&7)
  __shared__ ushort As[128 * 32];
  __shared__ ushort Bs[128 * 32];
  const int bm = blockIdx.y * 128;
  const int bn = blockIdx.x * 128;
  const int tid = threadIdx.x;
  const int w = tid >> 6, lane = tid & 63;
  const int g = lane >> 4, cc = lane & 15;
  const int wm = (w >> 1) * 64, wn = (w & 1) * 64;

  f32x4 acc[4][4];
#pragma unroll
  for (int i = 0; i < 4; ++i)
#pragma unroll
    for (int j = 0; j < 4; ++j) acc[i][j] = (f32x4)0.0f;

  for (int k0 = 0; k0 < K; k0 += 32) {
#pragma unroll
    for (int j = 0; j < 2; ++j) {
      int cbase = w * 128 + j * 64;
      int cid = cbase + lane;
      int row = cid & 127, kb = cid >> 7;
      async_cp16(A + (size_t)(bm + row) * K + k0 + kb * 8, &As[cbase * 8]);
      async_cp16(W + (size_t)(bn + row) * K + k0 + kb * 8, &Bs[cbase * 8]);
    }
    __syncthreads();
    bf16x8 af[4], bfr[4];
#pragma unroll
    for (int mi = 0; mi < 4; ++mi)
      af[mi] = *(const bf16x8*)&As[(g * 128 + wm + mi * 16 + cc) * 8];
#pragma unroll
    for (int ni = 0; ni < 4; ++ni)
      bfr[ni] = *(const bf16x8*)&Bs[(g * 128 + wn + ni * 16 + cc) * 8];
#pragma unroll
    for (int mi = 0; mi < 4; ++mi)
#pragma unroll
      for (int ni = 0; ni < 4; ++ni)
        acc[mi][ni] = __builtin_amdgcn_mfma_f32_16x16x32_bf16(af[mi], bfr[ni], acc[mi][ni], 0, 0, 0);
    __syncthreads();
  }

#pragma unroll
  for (int mi = 0; mi < 4; ++mi) {
#pragma unroll
    for (int ni = 0; ni < 4; ++ni) {
#pragma unroll
      for (int r = 0; r < 4; ++r) {
        int row = bm + wm + mi * 16 + g * 4 + r;   // C/D layout: row=(lane>>4)*4+reg
        int col = bn + wn + ni * 16 + cc;          //             col=lane&15
        float val = acc[mi][ni][r];
        if (MODE == 0) {
          ((ushort*)Cout)[(size_t)row * N + col] = f2bf(val);
        } else if (MODE == 1) {
          ((float*)Cout)[(size_t)row * N + col] = val;
        } else {
          int b = row >> 11, s = row & 2047;
          int h = col >> 6, d = col & 63;
          ((ushort*)Cout)[(size_t)((b * 16 + h) * 64 + d) * 2048 + s] = f2bf(val);
        }
      }
    }
  }
}

// Flash attention. Qp/Kp: [B*S, 1024] bf16 (head h at cols h*64..h*64+63).
// Vt: [B*H, 64, 2048] bf16 (pre-transposed). mask: [B,2048] int32 (0 -> -1e9).
// mh out: [B*S, 1024] bf16 merged heads.
__global__ __launch_bounds__(256) void attn_kernel(const ushort* __restrict__ Qp,
                                                   const ushort* __restrict__ Kp,
                                                   const ushort* __restrict__ Vt,
                                                   const int* __restrict__ mask,
                                                   ushort* __restrict__ mh) {
  constexpr int S = 2048, DM = 1024, DK = 64;
  __shared__ ushort q_lds[64 * 64];     // chunk-blocked [kb][row64][8]
  __shared__ ushort k_lds[128 * 64];    // chunk-blocked [kb][row128][8]
  __shared__ ushort vt_lds[64 * 128];   // chunk-blocked on kpos: [(kpos>>3)][d64][8]
  __shared__ ushort p_lds[64 * 136];    // row-major [qrow64][128+8pad], wave-private rows

  const int qt = blockIdx.x;  // 0..31
  const int bh = blockIdx.y;  // 0..63
  const int b = bh >> 4, h = bh & 15;
  const int tid = threadIdx.x;
  const int w = tid >> 6, lane = tid & 63;
  const int g = lane >> 4, cc = lane & 15;

  // stage Q once: 64 rows x 64 d = 512 chunks
  const size_t qrowbase = (size_t)(b * S + qt * 64) * DM + h * DK;
#pragma unroll
  for (int j = 0; j < 2; ++j) {
    int cbase = w * 128 + j * 64;
    int cid = cbase + lane;
    int row = cid & 63, kb = cid >> 6;
    async_cp16(Qp + qrowbase + (size_t)row * DM + kb * 8, &q_lds[cbase * 8]);
  }

  f32x4 o_acc[4];
#pragma unroll
  for (int i = 0; i < 4; ++i) o_acc[i] = (f32x4)0.0f;
  float m_i[4], l_i[4];
#pragma unroll
  for (int r = 0; r < 4; ++r) { m_i[r] = -1e30f; l_i[r] = 0.0f; }
  bf16x8 qf[2];

  const int* maskb = mask + b * S;

  for (int kt = 0; kt < S / 128; ++kt) {
    if (kt) __syncthreads();  // prev tile's reads done before restaging
    const size_t krowbase = (size_t)(b * S + kt * 128) * DM + h * DK;
    const size_t vrowbase = (size_t)bh * DK * S + kt * 128;
#pragma unroll
    for (int j = 0; j < 4; ++j) {
      int cbase = w * 256 + j * 64;
      int cid = cbase + lane;
      {
        int row = cid & 127, kb = cid >> 7;
        async_cp16(Kp + krowbase + (size_t)row * DM + kb * 8, &k_lds[cbase * 8]);
      }
      {
        int d = cid & 63, kb2 = cid >> 6;
        async_cp16(Vt + vrowbase + (size_t)d * S + kb2 * 8, &vt_lds[cbase * 8]);
      }
    }
    __syncthreads();  // staging drained (includes Q on first iter)

    if (kt == 0) {
#pragma unroll
      for (int ks = 0; ks < 2; ++ks)
        qf[ks] = *(const bf16x8*)&q_lds[((ks * 4 + g) * 64 + w * 16 + cc) * 8];
    }

    // S = Q K^T  (wave handles 16 q-rows x 128 keys)
    f32x4 sacc[8];
#pragma unroll
    for (int ni = 0; ni < 8; ++ni) sacc[ni] = (f32x4)0.0f;
#pragma unroll
    for (int ks = 0; ks < 2; ++ks) {
#pragma unroll
      for (int ni = 0; ni < 8; ++ni) {
        bf16x8 kf = *(const bf16x8*)&k_lds[((ks * 4 + g) * 128 + ni * 16 + cc) * 8];
        sacc[ni] = __builtin_amdgcn_mfma_f32_16x16x32_bf16(qf[ks], kf, sacc[ni], 0, 0, 0);
      }
    }

    // scale + mask (exact -1e9 like reference)
#pragma unroll
    for (int ni = 0; ni < 8; ++ni) {
      int mv = maskb[kt * 128 + ni * 16 + cc];
#pragma unroll
      for (int r = 0; r < 4; ++r)
        sacc[ni][r] = mv ? sacc[ni][r] * 0.125f : -1e9f;
    }

    // online softmax: row stats live in 16-lane groups (C-layout row = g*4+r)
    float mnew[4];
#pragma unroll
    for (int r = 0; r < 4; ++r) {
      float m = sacc[0][r];
#pragma unroll
      for (int ni = 1; ni < 8; ++ni) m = fmaxf(m, sacc[ni][r]);
      m = fmaxf(m, __shfl_xor(m, 1, 64));
      m = fmaxf(m, __shfl_xor(m, 2, 64));
      m = fmaxf(m, __shfl_xor(m, 4, 64));
      m = fmaxf(m, __shfl_xor(m, 8, 64));
      float mn = fmaxf(m_i[r], m);
      float alpha = __expf(m_i[r] - mn);
      m_i[r] = mn;
      mnew[r] = mn;
      l_i[r] *= alpha;
#pragma unroll
      for (int nd = 0; nd < 4; ++nd) o_acc[nd][r] *= alpha;
    }

    // P = exp(S - m), write bf16 to wave-private LDS rows, accumulate row sums
    float rsum[4] = {0.0f, 0.0f, 0.0f, 0.0f};
#pragma unroll
    for (int ni = 0; ni < 8; ++ni) {
#pragma unroll
      for (int r = 0; r < 4; ++r) {
        float p = __expf(sacc[ni][r] - mnew[r]);
        rsum[r] += p;
        p_lds[(w * 16 + g * 4 + r) * 136 + ni * 16 + cc] = f2bf(p);
      }
    }
#pragma unroll
    for (int r = 0; r < 4; ++r) {
      float s = rsum[r];
      s += __shfl_xor(s, 1, 64);
      s += __shfl_xor(s, 2, 64);
      s += __shfl_xor(s, 4, 64);
      s += __shfl_xor(s, 8, 64);
      l_i[r] += s;
    }

    // O += P V   (P from LDS in A-layout, V^T in B-layout)
#pragma unroll
    for (int ks2 = 0; ks2 < 4; ++ks2) {
      bf16x8 pf = *(const bf16x8*)&p_lds[(w * 16 + cc) * 136 + ks2 * 32 + g * 8];
#pragma unroll
      for (int nd = 0; nd < 4; ++nd) {
        bf16x8 vf = *(const bf16x8*)&vt_lds[((ks2 * 4 + g) * 64 + nd * 16 + cc) * 8];
        o_acc[nd] = __builtin_amdgcn_mfma_f32_16x16x32_bf16(pf, vf, o_acc[nd], 0, 0, 0);
      }
    }
  }

  // epilogue: O / l -> mh
#pragma unroll
  for (int r = 0; r < 4; ++r) {
    float rl = 1.0f / l_i[r];
    int qrow = qt * 64 + w * 16 + g * 4 + r;
#pragma unroll
    for (int nd = 0; nd < 4; ++nd)
      mh[(size_t)(b * S + qrow) * DM + h * DK + nd * 16 + cc] = f2bf(o_acc[nd][r] * rl);
  }
}

extern "C" void kernel_launch(void* const* d_in, const int* in_sizes, int n_in,
                              void* d_out, int out_size, void* d_ws, size_t ws_size,
                              hipStream_t stream) {
  const float* q = (const float*)d_in[0];
  const float* k = (const float*)d_in[1];
  const float* v = (const float*)d_in[2];
  const int* mask = (const int*)d_in[3];
  const float* Wq = (const float*)d_in[4];
  const float* Wk = (const float*)d_in[5];
  const float* Wv = (const float*)d_in[6];
  const float* Wo = (const float*)d_in[7];

  const int M = 8192, Dm = 1024;

  char* ws = (char*)d_ws;
  ushort* bufA = (ushort*)(ws);                          // 16 MB: casted input / mh
  ushort* bufB = (ushort*)(ws + (size_t)(16 << 20));     // 16 MB: Qp
  ushort* bufC = (ushort*)(ws + (size_t)(32 << 20));     // 16 MB: Kp
  ushort* bufD = (ushort*)(ws + (size_t)(48 << 20));     // 16 MB: Vt (head-transposed)
  ushort* wqb = (ushort*)(ws + (size_t)(64 << 20));      // 4 x 2 MB weights
  ushort* wkb = wqb + (1 << 20);
  ushort* wvb = wkb + (1 << 20);
  ushort* wob = wvb + (1 << 20);

  dim3 blk(256);
  dim3 ggrid(Dm / 128, M / 128);

  // weights -> bf16
  cast_bf16_kernel<<<dim3(1024), blk, 0, stream>>>(Wq, wqb, Dm * Dm / 4);
  cast_bf16_kernel<<<dim3(1024), blk, 0, stream>>>(Wk, wkb, Dm * Dm / 4);
  cast_bf16_kernel<<<dim3(1024), blk, 0, stream>>>(Wv, wvb, Dm * Dm / 4);
  cast_bf16_kernel<<<dim3(1024), blk, 0, stream>>>(Wo, wob, Dm * Dm / 4);

  // Q projection
  cast_bf16_kernel<<<dim3(8192), blk, 0, stream>>>(q, bufA, M * Dm / 4);
  gemm_bt<0><<<ggrid, blk, 0, stream>>>(bufA, wqb, (void*)bufB, M, Dm, Dm);
  // K projection
  cast_bf16_kernel<<<dim3(8192), blk, 0, stream>>>(k, bufA, M * Dm / 4);
  gemm_bt<0><<<ggrid, blk, 0, stream>>>(bufA, wkb, (void*)bufC, M, Dm, Dm);
  // V projection (writes per-head transposed [B,H,d,S])
  cast_bf16_kernel<<<dim3(8192), blk, 0, stream>>>(v, bufA, M * Dm / 4);
  gemm_bt<2><<<ggrid, blk, 0, stream>>>(bufA, wvb, (void*)bufD, M, Dm, Dm);

  // flash attention -> mh (bufA)
  attn_kernel<<<dim3(32, 64), blk, 0, stream>>>(bufB, bufC, bufD, mask, bufA);

  // output projection -> fp32 d_out
  gemm_bt<1><<<ggrid, blk, 0, stream>>>(bufA, wob, d_out, M, Dm, Dm);
}

// Round 2
// 459.479 us; speedup vs baseline: 1.2536x; 1.2536x over previous
//
#include <hip/hip_runtime.h>

typedef __attribute__((ext_vector_type(4))) float f32x4;
typedef __attribute__((ext_vector_type(8))) __bf16 bf16x8;
typedef __attribute__((ext_vector_type(2))) __bf16 bf16x2;

#if defined(__has_builtin)
#if __has_builtin(__builtin_amdgcn_exp2f)
#define EXP2F(x) __builtin_amdgcn_exp2f(x)
#endif
#if __has_builtin(__builtin_amdgcn_cvt_pk_bf16_f32)
#define HAVE_CVT_PK 1
#endif
#endif
#ifndef EXP2F
#define EXP2F(x) __builtin_exp2f(x)
#endif

__device__ __forceinline__ ushort f2bf(float f) {
  unsigned int u = __float_as_uint(f);
  return (ushort)((u + 0x7FFFu + ((u >> 16) & 1u)) >> 16);
}

__device__ __forceinline__ uint pack_bf16(float a, float b) {
#ifdef HAVE_CVT_PK
  bf16x2 p = __builtin_amdgcn_cvt_pk_bf16_f32(a, b);
  return __builtin_bit_cast(uint, p);
#else
  return (uint)f2bf(a) | ((uint)f2bf(b) << 16);
#endif
}

// async global->LDS, 16B per lane; LDS dst is wave-uniform base (HW adds lane*16)
__device__ __forceinline__ void async_cp16(const void* g, void* l) {
  __builtin_amdgcn_global_load_lds(
      (const __attribute__((address_space(1))) void*)g,
      (__attribute__((address_space(3))) void*)l, 16, 0, 0);
}

// ---------------- casts ----------------

__global__ __launch_bounds__(256) void cast_bf16_kernel(const float* __restrict__ in,
                                                        ushort* __restrict__ out, int n4) {
  int i = blockIdx.x * 256 + threadIdx.x;
  if (i < n4) {
    float4 f = ((const float4*)in)[i];
    uint2 o;
    o.x = pack_bf16(f.x, f.y);
    o.y = pack_bf16(f.z, f.w);
    ((uint2*)out)[i] = o;
  }
}

__global__ __launch_bounds__(256) void cast3_kernel(const float* __restrict__ q,
                                                    const float* __restrict__ k,
                                                    const float* __restrict__ v,
                                                    ushort* qo, ushort* ko, ushort* vo) {
  int y = blockIdx.y;
  const float* in = y == 0 ? q : (y == 1 ? k : v);
  ushort* out = y == 0 ? qo : (y == 1 ? ko : vo);
  int i = blockIdx.x * 256 + threadIdx.x;
  float4 f = ((const float4*)in)[i];
  uint2 o;
  o.x = pack_bf16(f.x, f.y);
  o.y = pack_bf16(f.z, f.w);
  ((uint2*)out)[i] = o;
}

__global__ __launch_bounds__(256) void cast4_kernel(const float* __restrict__ a,
                                                    const float* __restrict__ b,
                                                    const float* __restrict__ c,
                                                    const float* __restrict__ d,
                                                    ushort* ao, ushort* bo, ushort* co, ushort* do_) {
  int y = blockIdx.y;
  const float* in = y == 0 ? a : (y == 1 ? b : (y == 2 ? c : d));
  ushort* out = y == 0 ? ao : (y == 1 ? bo : (y == 2 ? co : do_));
  int i = blockIdx.x * 256 + threadIdx.x;
  float4 f = ((const float4*)in)[i];
  uint2 o;
  o.x = pack_bf16(f.x, f.y);
  o.y = pack_bf16(f.z, f.w);
  ((uint2*)out)[i] = o;
}

// ---------------- GEMM: C[m,n] = sum_k A[m,k]*W[n,k], M=8192 N=K=1024 ----------------
// mode 0: bf16 out row-major; mode 1: fp32 out row-major;
// mode 2: bf16 out per-head transposed: out[((b*16+h)*64+d)*2048 + s]

__device__ __forceinline__ void gemm_body(const ushort* __restrict__ A,
                                          const ushort* __restrict__ W,
                                          void* __restrict__ Cout, int mode) {
  constexpr int N = 1024, K = 1024;
  __shared__ ushort As[128 * 32];
  __shared__ ushort Bs[128 * 32];
  const int bm = blockIdx.y * 128;
  const int bn = blockIdx.x * 128;
  const int tid = threadIdx.x;
  const int w = tid >> 6, lane = tid & 63;
  const int g = lane >> 4, cc = lane & 15;
  const int wm = (w >> 1) * 64, wn = (w & 1) * 64;

  f32x4 acc[4][4];
#pragma unroll
  for (int i = 0; i < 4; ++i)
#pragma unroll
    for (int j = 0; j < 4; ++j) acc[i][j] = (f32x4)0.0f;

  for (int k0 = 0; k0 < K; k0 += 32) {
#pragma unroll
    for (int j = 0; j < 2; ++j) {
      int cbase = w * 128 + j * 64;
      int cid = cbase + lane;
      int row = cid & 127, kb = cid >> 7;
      async_cp16(A + (size_t)(bm + row) * K + k0 + kb * 8, &As[cbase * 8]);
      async_cp16(W + (size_t)(bn + row) * K + k0 + kb * 8, &Bs[cbase * 8]);
    }
    __syncthreads();
    bf16x8 af[4], bfr[4];
#pragma unroll
    for (int mi = 0; mi < 4; ++mi)
      af[mi] = *(const bf16x8*)&As[(g * 128 + wm + mi * 16 + cc) * 8];
#pragma unroll
    for (int ni = 0; ni < 4; ++ni)
      bfr[ni] = *(const bf16x8*)&Bs[(g * 128 + wn + ni * 16 + cc) * 8];
#pragma unroll
    for (int mi = 0; mi < 4; ++mi)
#pragma unroll
      for (int ni = 0; ni < 4; ++ni)
        acc[mi][ni] = __builtin_amdgcn_mfma_f32_16x16x32_bf16(af[mi], bfr[ni], acc[mi][ni], 0, 0, 0);
    __syncthreads();
  }

#pragma unroll
  for (int mi = 0; mi < 4; ++mi) {
#pragma unroll
    for (int ni = 0; ni < 4; ++ni) {
#pragma unroll
      for (int r = 0; r < 4; ++r) {
        int row = bm + wm + mi * 16 + g * 4 + r;
        int col = bn + wn + ni * 16 + cc;
        float val = acc[mi][ni][r];
        if (mode == 0) {
          ((ushort*)Cout)[(size_t)row * N + col] = f2bf(val);
        } else if (mode == 1) {
          ((float*)Cout)[(size_t)row * N + col] = val;
        } else {
          int b = row >> 11, s = row & 2047;
          int h = col >> 6, d = col & 63;
          ((ushort*)Cout)[(size_t)((b * 16 + h) * 64 + d) * 2048 + s] = f2bf(val);
        }
      }
    }
  }
}

__global__ __launch_bounds__(256) void qkv_gemm_kernel(const ushort* qb, const ushort* kb,
                                                       const ushort* vb, const ushort* wq,
                                                       const ushort* wk, const ushort* wv,
                                                       ushort* Qp, ushort* Kp, ushort* Vt) {
  int z = blockIdx.z;
  const ushort* A = z == 0 ? qb : (z == 1 ? kb : vb);
  const ushort* W = z == 0 ? wq : (z == 1 ? wk : wv);
  void* C = z == 0 ? (void*)Qp : (z == 1 ? (void*)Kp : (void*)Vt);
  gemm_body(A, W, C, z == 2 ? 2 : 0);
}

__global__ __launch_bounds__(256) void gemm1_kernel(const ushort* A, const ushort* W,
                                                    void* C, int mode) {
  gemm_body(A, W, C, mode);
}

// ---------------- flash attention (S^T form) ----------------
// Qp/Kp: [B*S, 1024] bf16 row-major (head h at cols h*64..). Vt: [B*H, 64, 2048] bf16.
// mask: [B, 2048] int32. mh: [B*S, 1024] bf16 merged heads.
// Block: 128 q-rows (4 waves x 32 q). Key tile: 64. Computes S^T = K*Q^T per tile,
// softmax stats per q live in cc lanes, P^T packed to LDS, O^T += V^T * P^T.
__global__ __launch_bounds__(256, 4) void attn_kernel(const ushort* __restrict__ Qp,
                                                      const ushort* __restrict__ Kp,
                                                      const ushort* __restrict__ Vt,
                                                      const int* __restrict__ mask,
                                                      ushort* __restrict__ mh) {
  constexpr int S = 2048, DM = 1024, DK = 64;
  __shared__ ushort k_lds[64 * 64];     // ((d>>3)*64 + key)*8 + (d&7)
  __shared__ ushort v_lds[64 * 64];     // ((k>>3)*64 + d)*8 + (k&7)
  __shared__ ushort pt_lds[4 * 2176];   // per-wave: P^T ((k>>3)*32 + q)*8 + (k&7); reused as O in epilogue

  const int bh = blockIdx.x;  // b*16+h ; linear id % 8 == bh % 8 -> same head on same XCD
  const int qt = blockIdx.y;  // 0..15
  const int b = bh >> 4, h = bh & 15;
  const int tid = threadIdx.x;
  const int w = tid >> 6, lane = tid & 63;
  const int g = lane >> 4, cc = lane & 15;
  ushort* ptw = &pt_lds[w * 2176];

  const int q0 = qt * 128 + w * 32;  // wave's first q row within batch
  // Q fragments direct from global (B-operand layout), held in regs for whole kernel
  bf16x8 qf[2][2];
#pragma unroll
  for (int ni = 0; ni < 2; ++ni) {
    size_t row = (size_t)(b * S + q0 + ni * 16 + cc);
#pragma unroll
    for (int ks = 0; ks < 2; ++ks)
      qf[ks][ni] = *(const bf16x8*)&Qp[row * DM + h * DK + ks * 32 + g * 8];
  }

  f32x4 o_acc[4][2];
#pragma unroll
  for (int i = 0; i < 4; ++i)
#pragma unroll
    for (int j = 0; j < 2; ++j) o_acc[i][j] = (f32x4)0.0f;
  float m_i[2] = {-3e38f, -3e38f};
  float l_p[2] = {0.0f, 0.0f};  // lane-partial row sums
  const int* maskb = mask + b * S;
  const float csc = 0.18033688011112042f;  // 0.125 * log2(e)

  for (int kt = 0; kt < S / 64; ++kt) {
    if (kt) __syncthreads();
#pragma unroll
    for (int j = 0; j < 2; ++j) {
      int cb = j * 256 + w * 64;
      int cid = cb + lane;
      async_cp16(Kp + (size_t)(b * S + kt * 64 + (cid & 63)) * DM + h * DK + (cid >> 6) * 8,
                 &k_lds[cb * 8]);
      async_cp16(Vt + (size_t)(bh * DK + (cid & 63)) * S + kt * 64 + (cid >> 6) * 8,
                 &v_lds[cb * 8]);
    }
    __syncthreads();

    // S^T = K * Q^T : tiles [key 4][q 2]
    f32x4 sacc[4][2];
#pragma unroll
    for (int mi = 0; mi < 4; ++mi)
#pragma unroll
      for (int ni = 0; ni < 2; ++ni) sacc[mi][ni] = (f32x4)0.0f;
#pragma unroll
    for (int ks = 0; ks < 2; ++ks)
#pragma unroll
      for (int mi = 0; mi < 4; ++mi) {
        bf16x8 kf = *(const bf16x8*)&k_lds[((ks * 4 + g) * 64 + mi * 16 + cc) * 8];
        sacc[mi][0] = __builtin_amdgcn_mfma_f32_16x16x32_bf16(kf, qf[ks][0], sacc[mi][0], 0, 0, 0);
        sacc[mi][1] = __builtin_amdgcn_mfma_f32_16x16x32_bf16(kf, qf[ks][1], sacc[mi][1], 0, 0, 0);
      }

    // mask + scale into exp2 domain, per-lane tile max
    float mx[2] = {-3e38f, -3e38f};
#pragma unroll
    for (int mi = 0; mi < 4; ++mi) {
      int4 mv = *(const int4*)&maskb[kt * 64 + mi * 16 + g * 4];
      const int* mvp = &mv.x;
#pragma unroll
      for (int r = 0; r < 4; ++r) {
        bool keep = mvp[r] != 0;
#pragma unroll
        for (int ni = 0; ni < 2; ++ni) {
          float t = sacc[mi][ni][r] * csc;
          t = keep ? t : -1e9f;
          sacc[mi][ni][r] = t;
          mx[ni] = fmaxf(mx[ni], t);
        }
      }
    }
    float mn[2];
#pragma unroll
    for (int ni = 0; ni < 2; ++ni) {
      float m = mx[ni];
      m = fmaxf(m, __shfl_xor(m, 16, 64));
      m = fmaxf(m, __shfl_xor(m, 32, 64));
      mn[ni] = fmaxf(m_i[ni], m);
      float al = EXP2F(m_i[ni] - mn[ni]);
      m_i[ni] = mn[ni];
      l_p[ni] *= al;
#pragma unroll
      for (int md = 0; md < 4; ++md)
#pragma unroll
        for (int r = 0; r < 4; ++r) o_acc[md][ni][r] *= al;
    }

    // P = exp2(s - m); pack key-pairs; write P^T to this wave's LDS region
#pragma unroll
    for (int mi = 0; mi < 4; ++mi)
#pragma unroll
      for (int ni = 0; ni < 2; ++ni) {
        float p0 = EXP2F(sacc[mi][ni][0] - mn[ni]);
        float p1 = EXP2F(sacc[mi][ni][1] - mn[ni]);
        float p2 = EXP2F(sacc[mi][ni][2] - mn[ni]);
        float p3 = EXP2F(sacc[mi][ni][3] - mn[ni]);
        l_p[ni] += (p0 + p1) + (p2 + p3);
        int base = ((mi * 2 + (g >> 1)) * 32 + ni * 16 + cc) * 8 + (g & 1) * 4;
        *(uint*)&ptw[base] = pack_bf16(p0, p1);
        *(uint*)&ptw[base + 2] = pack_bf16(p2, p3);
      }

    // O^T += V^T * P^T  (same-wave LDS RAW; compiler inserts lgkm waits, no barrier)
#pragma unroll
    for (int ks = 0; ks < 2; ++ks) {
      bf16x8 ptf[2];
#pragma unroll
      for (int ni = 0; ni < 2; ++ni)
        ptf[ni] = *(const bf16x8*)&ptw[((ks * 4 + g) * 32 + ni * 16 + cc) * 8];
#pragma unroll
      for (int md = 0; md < 4; ++md) {
        bf16x8 vf = *(const bf16x8*)&v_lds[((ks * 4 + g) * 64 + md * 16 + cc) * 8];
        o_acc[md][0] = __builtin_amdgcn_mfma_f32_16x16x32_bf16(vf, ptf[0], o_acc[md][0], 0, 0, 0);
        o_acc[md][1] = __builtin_amdgcn_mfma_f32_16x16x32_bf16(vf, ptf[1], o_acc[md][1], 0, 0, 0);
      }
    }
  }

  // finalize l, normalize, transpose O^T -> O through LDS, coalesced store
  float rl[2];
#pragma unroll
  for (int ni = 0; ni < 2; ++ni) {
    float l = l_p[ni];
    l += __shfl_xor(l, 16, 64);
    l += __shfl_xor(l, 32, 64);
    rl[ni] = 1.0f / l;
  }
#pragma unroll
  for (int md = 0; md < 4; ++md)
#pragma unroll
    for (int ni = 0; ni < 2; ++ni) {
      int ql = ni * 16 + cc;
      int dbase = md * 16 + g * 4;
      *(uint*)&ptw[ql * 68 + dbase] =
          pack_bf16(o_acc[md][ni][0] * rl[ni], o_acc[md][ni][1] * rl[ni]);
      *(uint*)&ptw[ql * 68 + dbase + 2] =
          pack_bf16(o_acc[md][ni][2] * rl[ni], o_acc[md][ni][3] * rl[ni]);
    }
#pragma unroll
  for (int pass = 0; pass < 4; ++pass) {
    int ql = pass * 8 + (lane >> 3);
    int dc = lane & 7;
    uint4 val = *(const uint4*)&ptw[ql * 68 + dc * 8];
    *(uint4*)&mh[(size_t)(b * S + q0 + ql) * DM + h * DK + dc * 8] = val;
  }
}

// ---------------- launch ----------------

extern "C" void kernel_launch(void* const* d_in, const int* in_sizes, int n_in,
                              void* d_out, int out_size, void* d_ws, size_t ws_size,
                              hipStream_t stream) {
  const float* q = (const float*)d_in[0];
  const float* k = (const float*)d_in[1];
  const float* v = (const float*)d_in[2];
  const int* mask = (const int*)d_in[3];
  const float* Wq = (const float*)d_in[4];
  const float* Wk = (const float*)d_in[5];
  const float* Wv = (const float*)d_in[6];
  const float* Wo = (const float*)d_in[7];

  const int M = 8192, Dm = 1024;
  const size_t MB = 1 << 20;

  char* ws = (char*)d_ws;
  ushort* Qp = (ushort*)(ws);
  ushort* Kp = (ushort*)(ws + 16 * MB);
  ushort* Vt = (ushort*)(ws + 32 * MB);
  ushort* wqb = (ushort*)(ws + 48 * MB);
  ushort* wkb = wqb + (1 << 20);
  ushort* wvb = wkb + (1 << 20);
  ushort* wob = wvb + (1 << 20);
  ushort* inbase = (ushort*)(ws + 56 * MB);

  dim3 blk(256);
  dim3 ggrid(Dm / 128, M / 128);

  cast4_kernel<<<dim3(1024, 4), blk, 0, stream>>>(Wq, Wk, Wv, Wo, wqb, wkb, wvb, wob);

  ushort* mh;
  if (ws_size >= 104 * MB) {
    // fast path: cast q,k,v at once, single fused QKV projection launch
    ushort* qb = inbase;
    ushort* kb = inbase + 8 * MB;   // ushort units: 16MB bytes
    ushort* vb = inbase + 16 * MB;
    cast3_kernel<<<dim3(8192, 3), blk, 0, stream>>>(q, k, v, qb, kb, vb);
    qkv_gemm_kernel<<<dim3(Dm / 128, M / 128, 3), blk, 0, stream>>>(qb, kb, vb, wqb, wkb, wvb,
                                                                    Qp, Kp, Vt);
    mh = qb;  // qb free after projections
  } else {
    // slow path: sequential casts through one 16MB buffer
    ushort* bufA = inbase;
    cast_bf16_kernel<<<dim3(8192), blk, 0, stream>>>(q, bufA, M * Dm / 4);
    gemm1_kernel<<<ggrid, blk, 0, stream>>>(bufA, wqb, (void*)Qp, 0);
    cast_bf16_kernel<<<dim3(8192), blk, 0, stream>>>(k, bufA, M * Dm / 4);
    gemm1_kernel<<<ggrid, blk, 0, stream>>>(bufA, wkb, (void*)Kp, 0);
    cast_bf16_kernel<<<dim3(8192), blk, 0, stream>>>(v, bufA, M * Dm / 4);
    gemm1_kernel<<<ggrid, blk, 0, stream>>>(bufA, wvb, (void*)Vt, 2);
    mh = bufA;
  }

  attn_kernel<<<dim3(64, 16), blk, 0, stream>>>(Qp, Kp, Vt, mask, mh);
  gemm1_kernel<<<ggrid, blk, 0, stream>>>(mh, wob, d_out, 1);
}

// Round 3
// 445.791 us; speedup vs baseline: 1.2921x; 1.0307x over previous
//
#include <hip/hip_runtime.h>
#include <math.h>

typedef __attribute__((ext_vector_type(4))) float f32x4;
typedef __attribute__((ext_vector_type(8))) __bf16 bf16x8;
typedef __attribute__((ext_vector_type(2))) __bf16 bf16x2;

#ifndef __has_builtin
#define __has_builtin(x) 0
#endif

#if __has_builtin(__builtin_amdgcn_exp2f)
#define EXP2F(x) __builtin_amdgcn_exp2f(x)
#else
#define EXP2F(x) exp2f(x)
#endif

__device__ __forceinline__ ushort f2bf(float f) {
  return (ushort)((__float_as_uint(f) + 0x8000u) >> 16);  // round-half-up
}

__device__ __forceinline__ uint pack_bf16(float a, float b) {
#if __has_builtin(__builtin_amdgcn_cvt_pk_bf16_f32)
  bf16x2 p = __builtin_amdgcn_cvt_pk_bf16_f32(a, b);
  return __builtin_bit_cast(uint, p);
#elif __has_builtin(__builtin_amdgcn_perm)
  uint au = __float_as_uint(a) + 0x8000u;
  uint bu = __float_as_uint(b) + 0x8000u;
  // D.b0=a.b2 D.b1=a.b3 D.b2=b.b2 D.b3=b.b3 ; codes 0-3 pick arg1, 4-7 pick arg0
  return __builtin_amdgcn_perm(bu, au, 0x07060302u);
#else
  return (uint)f2bf(a) | ((uint)f2bf(b) << 16);
#endif
}

// async global->LDS, 16B per lane; LDS dst is wave-uniform base (HW adds lane*16)
__device__ __forceinline__ void async_cp16(const void* g, void* l) {
  __builtin_amdgcn_global_load_lds(
      (const __attribute__((address_space(1))) void*)g,
      (__attribute__((address_space(3))) void*)l, 16, 0, 0);
}

// ---------------- small prep kernels ----------------

__global__ __launch_bounds__(256) void bias_kernel(const int* __restrict__ mask,
                                                   float* __restrict__ bias) {
  int i = blockIdx.x * 256 + threadIdx.x;  // 8192 total
  bias[i] = mask[i] ? 0.0f : -1e9f;
}

__global__ __launch_bounds__(256) void cast3_kernel(const float* __restrict__ q,
                                                    const float* __restrict__ k,
                                                    const float* __restrict__ v,
                                                    ushort* qo, ushort* ko, ushort* vo) {
  int y = blockIdx.y;
  const float* in = y == 0 ? q : (y == 1 ? k : v);
  ushort* out = y == 0 ? qo : (y == 1 ? ko : vo);
  int i = blockIdx.x * 256 + threadIdx.x;
  float4 f = ((const float4*)in)[i];
  uint2 o;
  o.x = pack_bf16(f.x, f.y);
  o.y = pack_bf16(f.z, f.w);
  ((uint2*)out)[i] = o;
}

__global__ __launch_bounds__(256) void cast4_kernel(const float* __restrict__ a,
                                                    const float* __restrict__ b,
                                                    const float* __restrict__ c,
                                                    const float* __restrict__ d,
                                                    ushort* ao, ushort* bo, ushort* co, ushort* do_) {
  int y = blockIdx.y;
  const float* in = y == 0 ? a : (y == 1 ? b : (y == 2 ? c : d));
  ushort* out = y == 0 ? ao : (y == 1 ? bo : (y == 2 ? co : do_));
  int i = blockIdx.x * 256 + threadIdx.x;
  float4 f = ((const float4*)in)[i];
  uint2 o;
  o.x = pack_bf16(f.x, f.y);
  o.y = pack_bf16(f.z, f.w);
  ((uint2*)out)[i] = o;
}

// ---------------- GEMM: C[m,n] = sum_k A[m,k]*W[n,k], M=8192 N=K=1024 ----------------
// mode 0: bf16 out row-major; mode 1: fp32 out row-major;
// mode 2: bf16 out per-head transposed: out[((b*16+h)*64+d)*2048 + s]
// mode 3: bf16 out row-major, scaled by 0.125*log2(e)  (Q projection)

__device__ __forceinline__ void gemm_body(const ushort* __restrict__ A,
                                          const ushort* __restrict__ W,
                                          void* __restrict__ Cout, int mode) {
  constexpr int N = 1024, K = 1024;
  __shared__ ushort As[128 * 32];
  __shared__ ushort Bs[128 * 32];
  const int bm = blockIdx.y * 128;
  const int bn = blockIdx.x * 128;
  const int tid = threadIdx.x;
  const int w = tid >> 6, lane = tid & 63;
  const int g = lane >> 4, cc = lane & 15;
  const int wm = (w >> 1) * 64, wn = (w & 1) * 64;

  f32x4 acc[4][4];
#pragma unroll
  for (int i = 0; i < 4; ++i)
#pragma unroll
    for (int j = 0; j < 4; ++j) acc[i][j] = (f32x4)0.0f;

  for (int k0 = 0; k0 < K; k0 += 32) {
#pragma unroll
    for (int j = 0; j < 2; ++j) {
      int cbase = w * 128 + j * 64;
      int cid = cbase + lane;
      int row = cid & 127, kb = cid >> 7;
      async_cp16(A + (size_t)(bm + row) * K + k0 + kb * 8, &As[cbase * 8]);
      async_cp16(W + (size_t)(bn + row) * K + k0 + kb * 8, &Bs[cbase * 8]);
    }
    __syncthreads();
    bf16x8 af[4], bfr[4];
#pragma unroll
    for (int mi = 0; mi < 4; ++mi)
      af[mi] = *(const bf16x8*)&As[(g * 128 + wm + mi * 16 + cc) * 8];
#pragma unroll
    for (int ni = 0; ni < 4; ++ni)
      bfr[ni] = *(const bf16x8*)&Bs[(g * 128 + wn + ni * 16 + cc) * 8];
#pragma unroll
    for (int mi = 0; mi < 4; ++mi)
#pragma unroll
      for (int ni = 0; ni < 4; ++ni)
        acc[mi][ni] = __builtin_amdgcn_mfma_f32_16x16x32_bf16(af[mi], bfr[ni], acc[mi][ni], 0, 0, 0);
    __syncthreads();
  }

  const float qsc = 0.18033688011112042f;
#pragma unroll
  for (int mi = 0; mi < 4; ++mi) {
#pragma unroll
    for (int ni = 0; ni < 4; ++ni) {
#pragma unroll
      for (int r = 0; r < 4; ++r) {
        int row = bm + wm + mi * 16 + g * 4 + r;
        int col = bn + wn + ni * 16 + cc;
        float val = acc[mi][ni][r];
        if (mode == 0) {
          ((ushort*)Cout)[(size_t)row * N + col] = f2bf(val);
        } else if (mode == 1) {
          ((float*)Cout)[(size_t)row * N + col] = val;
        } else if (mode == 3) {
          ((ushort*)Cout)[(size_t)row * N + col] = f2bf(val * qsc);
        } else {
          int b = row >> 11, s = row & 2047;
          int h = col >> 6, d = col & 63;
          ((ushort*)Cout)[(size_t)((b * 16 + h) * 64 + d) * 2048 + s] = f2bf(val);
        }
      }
    }
  }
}

__global__ __launch_bounds__(256) void qkv_gemm_kernel(const ushort* qb, const ushort* kb,
                                                       const ushort* vb, const ushort* wq,
                                                       const ushort* wk, const ushort* wv,
                                                       ushort* Qp, ushort* Kp, ushort* Vt) {
  int z = blockIdx.z;
  const ushort* A = z == 0 ? qb : (z == 1 ? kb : vb);
  const ushort* W = z == 0 ? wq : (z == 1 ? wk : wv);
  void* C = z == 0 ? (void*)Qp : (z == 1 ? (void*)Kp : (void*)Vt);
  gemm_body(A, W, C, z == 2 ? 2 : (z == 0 ? 3 : 0));
}

__global__ __launch_bounds__(256) void gemm1_kernel(const ushort* A, const ushort* W,
                                                    void* C, int mode) {
  gemm_body(A, W, C, mode);
}

// ---------------- flash attention (S^T form, exp2 domain) ----------------
// Qp: [B*S,1024] bf16 PRE-SCALED by 0.125*log2e. Kp: [B*S,1024] bf16.
// Vt: [B*H,64,2048] bf16. bias: [B,2048] fp32 (0 or -1e9). mh: [B*S,1024] bf16.
// Block: 128 q (4 waves x 32 q). Key tile 64. S^T = K*Q^T; l via ones-MFMA.
__global__ __launch_bounds__(256, 4) void attn_kernel(const ushort* __restrict__ Qp,
                                                      const ushort* __restrict__ Kp,
                                                      const ushort* __restrict__ Vt,
                                                      const float* __restrict__ bias,
                                                      ushort* __restrict__ mh) {
  constexpr int S = 2048, DM = 1024, DK = 64;
  __shared__ ushort k_lds[64 * 64];     // ((d>>3)*64 + key)*8 + (d&7)
  __shared__ ushort v_lds[64 * 64];     // ((k>>3)*64 + d)*8 + (k&7)
  __shared__ ushort pt_lds[4 * 2176];   // per-wave P^T ((k>>3)*32 + q)*8 + (k&7); O in epilogue

  const int bh = blockIdx.x;  // b*16+h ; id%8==bh%8 keeps a head's K/V on one XCD
  const int qt = blockIdx.y;
  const int b = bh >> 4, h = bh & 15;
  const int tid = threadIdx.x;
  const int w = tid >> 6, lane = tid & 63;
  const int g = lane >> 4, cc = lane & 15;
  ushort* ptw = &pt_lds[w * 2176];

  const int q0 = qt * 128 + w * 32;
  bf16x8 qf[2][2];
#pragma unroll
  for (int ni = 0; ni < 2; ++ni) {
    size_t row = (size_t)(b * S + q0 + ni * 16 + cc);
#pragma unroll
    for (int ks = 0; ks < 2; ++ks)
      qf[ks][ni] = *(const bf16x8*)&Qp[row * DM + h * DK + ks * 32 + g * 8];
  }

  bf16x8 ones;
#pragma unroll
  for (int i = 0; i < 8; ++i) ones[i] = (__bf16)1.0f;

  f32x4 o_acc[4][2];
#pragma unroll
  for (int i = 0; i < 4; ++i)
#pragma unroll
    for (int j = 0; j < 2; ++j) o_acc[i][j] = (f32x4)0.0f;
  f32x4 l_acc[2] = {(f32x4)0.0f, (f32x4)0.0f};
  float m_i[2] = {-3e38f, -3e38f};
  const float* biasb = bias + b * S;

  for (int kt = 0; kt < S / 64; ++kt) {
    if (kt) __syncthreads();
#pragma unroll
    for (int j = 0; j < 2; ++j) {
      int cb = j * 256 + w * 64;
      int cid = cb + lane;
      async_cp16(Kp + (size_t)(b * S + kt * 64 + (cid & 63)) * DM + h * DK + (cid >> 6) * 8,
                 &k_lds[cb * 8]);
      async_cp16(Vt + (size_t)(bh * DK + (cid & 63)) * S + kt * 64 + (cid >> 6) * 8,
                 &v_lds[cb * 8]);
    }
    __syncthreads();

    // S^T = K * Q^T : tiles [key 4][q 2]
    f32x4 sacc[4][2];
#pragma unroll
    for (int mi = 0; mi < 4; ++mi)
#pragma unroll
      for (int ni = 0; ni < 2; ++ni) sacc[mi][ni] = (f32x4)0.0f;
#pragma unroll
    for (int ks = 0; ks < 2; ++ks)
#pragma unroll
      for (int mi = 0; mi < 4; ++mi) {
        bf16x8 kf = *(const bf16x8*)&k_lds[((ks * 4 + g) * 64 + mi * 16 + cc) * 8];
        sacc[mi][0] = __builtin_amdgcn_mfma_f32_16x16x32_bf16(kf, qf[ks][0], sacc[mi][0], 0, 0, 0);
        sacc[mi][1] = __builtin_amdgcn_mfma_f32_16x16x32_bf16(kf, qf[ks][1], sacc[mi][1], 0, 0, 0);
      }

    // additive mask bias (fp32 add: s + (-1e9) == -1e9 exactly) + per-lane max
    float mx[2] = {-3e38f, -3e38f};
#pragma unroll
    for (int mi = 0; mi < 4; ++mi) {
      float4 bv = *(const float4*)&biasb[kt * 64 + mi * 16 + g * 4];
      const float* bvp = &bv.x;
#pragma unroll
      for (int r = 0; r < 4; ++r) {
#pragma unroll
        for (int ni = 0; ni < 2; ++ni) {
          float t = sacc[mi][ni][r] + bvp[r];
          sacc[mi][ni][r] = t;
          mx[ni] = fmaxf(mx[ni], t);
        }
      }
    }
    float mn[2];
#pragma unroll
    for (int ni = 0; ni < 2; ++ni) {
      float m = mx[ni];
      m = fmaxf(m, __shfl_xor(m, 16, 64));
      m = fmaxf(m, __shfl_xor(m, 32, 64));
      mn[ni] = fmaxf(m_i[ni], m);
      float al = EXP2F(m_i[ni] - mn[ni]);
      m_i[ni] = mn[ni];
      l_acc[ni][0] *= al;  // only reg0 is read at the end
#pragma unroll
      for (int md = 0; md < 4; ++md)
#pragma unroll
        for (int r = 0; r < 4; ++r) o_acc[md][ni][r] *= al;
    }

    // P = exp2(t - m); one b64 write per (mi,ni): 4 consecutive keys
#pragma unroll
    for (int mi = 0; mi < 4; ++mi)
#pragma unroll
      for (int ni = 0; ni < 2; ++ni) {
        float p0 = EXP2F(sacc[mi][ni][0] - mn[ni]);
        float p1 = EXP2F(sacc[mi][ni][1] - mn[ni]);
        float p2 = EXP2F(sacc[mi][ni][2] - mn[ni]);
        float p3 = EXP2F(sacc[mi][ni][3] - mn[ni]);
        uint2 pv;
        pv.x = pack_bf16(p0, p1);
        pv.y = pack_bf16(p2, p3);
        int base = ((mi * 2 + (g >> 1)) * 32 + ni * 16 + cc) * 8 + (g & 1) * 4;
        *(uint2*)&ptw[base] = pv;
      }

    // O^T += V^T * P^T ; l += ones * P^T  (same-wave LDS RAW; compiler inserts waits)
#pragma unroll
    for (int ks = 0; ks < 2; ++ks) {
      bf16x8 ptf[2];
#pragma unroll
      for (int ni = 0; ni < 2; ++ni)
        ptf[ni] = *(const bf16x8*)&ptw[((ks * 4 + g) * 32 + ni * 16 + cc) * 8];
      l_acc[0] = __builtin_amdgcn_mfma_f32_16x16x32_bf16(ones, ptf[0], l_acc[0], 0, 0, 0);
      l_acc[1] = __builtin_amdgcn_mfma_f32_16x16x32_bf16(ones, ptf[1], l_acc[1], 0, 0, 0);
#pragma unroll
      for (int md = 0; md < 4; ++md) {
        bf16x8 vf = *(const bf16x8*)&v_lds[((ks * 4 + g) * 64 + md * 16 + cc) * 8];
        o_acc[md][0] = __builtin_amdgcn_mfma_f32_16x16x32_bf16(vf, ptf[0], o_acc[md][0], 0, 0, 0);
        o_acc[md][1] = __builtin_amdgcn_mfma_f32_16x16x32_bf16(vf, ptf[1], o_acc[md][1], 0, 0, 0);
      }
    }
  }

  // normalize (l from MFMA row-sum: every lane's reg0 holds its q-column's sum)
  float rl[2];
#pragma unroll
  for (int ni = 0; ni < 2; ++ni) rl[ni] = 1.0f / l_acc[ni][0];

  // transpose O^T -> O through this wave's LDS, coalesced store
#pragma unroll
  for (int md = 0; md < 4; ++md)
#pragma unroll
    for (int ni = 0; ni < 2; ++ni) {
      int ql = ni * 16 + cc;
      int dbase = md * 16 + g * 4;
      *(uint*)&ptw[ql * 68 + dbase] =
          pack_bf16(o_acc[md][ni][0] * rl[ni], o_acc[md][ni][1] * rl[ni]);
      *(uint*)&ptw[ql * 68 + dbase + 2] =
          pack_bf16(o_acc[md][ni][2] * rl[ni], o_acc[md][ni][3] * rl[ni]);
    }
#pragma unroll
  for (int pass = 0; pass < 4; ++pass) {
    int ql = pass * 8 + (lane >> 3);
    int dc = lane & 7;
    uint4 val = *(const uint4*)&ptw[ql * 68 + dc * 8];
    *(uint4*)&mh[(size_t)(b * S + q0 + ql) * DM + h * DK + dc * 8] = val;
  }
}

// ---------------- launch ----------------
// ws layout (needs 73 MB, proven available by round-2 run):
//   0-16 Qp | 16-32 Kp | 32-48 Vt | 48-56 weights | 56 bias(32KB) | 57-73 vb->mh
// d_out (32 MB fp32) doubles as q/k bf16 cast scratch until the final GEMM.

extern "C" void kernel_launch(void* const* d_in, const int* in_sizes, int n_in,
                              void* d_out, int out_size, void* d_ws, size_t ws_size,
                              hipStream_t stream) {
  const float* q = (const float*)d_in[0];
  const float* k = (const float*)d_in[1];
  const float* v = (const float*)d_in[2];
  const int* mask = (const int*)d_in[3];
  const float* Wq = (const float*)d_in[4];
  const float* Wk = (const float*)d_in[5];
  const float* Wv = (const float*)d_in[6];
  const float* Wo = (const float*)d_in[7];

  const int M = 8192, Dm = 1024;
  const size_t MB = 1 << 20;

  char* ws = (char*)d_ws;
  ushort* Qp = (ushort*)(ws);
  ushort* Kp = (ushort*)(ws + 16 * MB);
  ushort* Vt = (ushort*)(ws + 32 * MB);
  ushort* wqb = (ushort*)(ws + 48 * MB);
  ushort* wkb = wqb + (1 << 20);
  ushort* wvb = wkb + (1 << 20);
  ushort* wob = wvb + (1 << 20);
  float* biasbuf = (float*)(ws + 56 * MB);
  ushort* vb = (ushort*)(ws + 57 * MB);
  ushort* mh = vb;  // vb dead after projections
  ushort* qb = (ushort*)d_out;
  ushort* kb = qb + (size_t)8 * 1024 * 1024;

  dim3 blk(256);
  dim3 ggrid(Dm / 128, M / 128);

  cast4_kernel<<<dim3(1024, 4), blk, 0, stream>>>(Wq, Wk, Wv, Wo, wqb, wkb, wvb, wob);
  bias_kernel<<<dim3(32), blk, 0, stream>>>(mask, biasbuf);
  cast3_kernel<<<dim3(8192, 3), blk, 0, stream>>>(q, k, v, qb, kb, vb);
  qkv_gemm_kernel<<<dim3(Dm / 128, M / 128, 3), blk, 0, stream>>>(qb, kb, vb, wqb, wkb, wvb,
                                                                  Qp, Kp, Vt);
  attn_kernel<<<dim3(64, 16), blk, 0, stream>>>(Qp, Kp, Vt, biasbuf, mh);
  gemm1_kernel<<<ggrid, blk, 0, stream>>>(mh, wob, d_out, 1);
}